// Round 6
// baseline (268.335 us; speedup 1.0000x reference)
//
#include <hip/hip_runtime.h>
#include <hip/hip_bf16.h>

#define T_TOKENS 65536
#define EMBED 256
#define DOWN 64
#define NE 10
#define NPAIR 100          // ordered (e0,e1) buckets, e0=top1
#define MAXQ 1280
#define XROW 72            // 64 + 8 bf16 pad

typedef __attribute__((ext_vector_type(8))) short short8;   // 8 bf16 (MFMA A/B frag)
typedef __attribute__((ext_vector_type(4))) float f32x4;    // MFMA C/D frag

__device__ inline unsigned short f2bf(float f) {            // RNE float->bf16
    unsigned u = __builtin_bit_cast(unsigned, f);
    u += 0x7fff + ((u >> 16) & 1);
    return (unsigned short)(u >> 16);
}
__device__ inline float bf2f(unsigned short h) {
    unsigned u = ((unsigned)h) << 16;
    return __builtin_bit_cast(float, u);
}

// ---------------- Kernel 0: pack w1/w2 into MFMA B-frag order, split hi/lo bf16 ------------------
__global__ __launch_bounds__(256) void pack_kernel(
    const float* __restrict__ w1, const float* __restrict__ w2,
    unsigned short* __restrict__ w1ph, unsigned short* __restrict__ w1pl,
    unsigned short* __restrict__ w2ph, unsigned short* __restrict__ w2pl)
{
    int gid = blockIdx.x * 256 + threadIdx.x;
    int lane = gid & 63;
    int fid = gid >> 6;
    int n16 = lane & 15;
    int kbase = ((lane >> 4) & 3) * 8;
    if (fid < 320) {            // w1: fid = (e*4 + ct)*8 + kb
        int kb = fid & 7, ect = fid >> 3;
        int ct = ect & 3, e = ect >> 2;
        int n = ct * 16 + n16;
        int k0 = kb * 32 + kbase;
#pragma unroll
        for (int j = 0; j < 8; ++j) {
            float v = w1[((size_t)e * EMBED + k0 + j) * DOWN + n];
            unsigned short h = f2bf(v);
            w1ph[(size_t)fid * 512 + lane * 8 + j] = h;
            w1pl[(size_t)fid * 512 + lane * 8 + j] = f2bf(v - bf2f(h));
        }
    } else if (fid < 640) {     // w2: f2 = (e*16 + ct)*2 + kb
        int f2 = fid - 320;
        int kb = f2 & 1, ect = f2 >> 1;
        int ct = ect & 15, e = ect >> 4;
        int n = ct * 16 + n16;
        int k0 = kb * 32 + kbase;
#pragma unroll
        for (int j = 0; j < 8; ++j) {
            float v = w2[((size_t)e * DOWN + k0 + j) * EMBED + n];
            unsigned short h = f2bf(v);
            w2ph[(size_t)f2 * 512 + lane * 8 + j] = h;
            w2pl[(size_t)f2 * 512 + lane * 8 + j] = f2bf(v - bf2f(h));
        }
    }
}

// ---------------- Kernel 1: gating; 128 tok/block, 2 threads/token; UNIFORM barriers -------------
__global__ __launch_bounds__(256) void gating_kernel(
    const float* __restrict__ x, const float* __restrict__ wg,
    int* __restrict__ pcount, float* __restrict__ importance,
    int* __restrict__ btok, float* __restrict__ bg0)
{
    __shared__ float Xs[2][128 * 33];    // 33.8 KB; stride 33 -> broadcast/conflict-free reads
    __shared__ int lcount[NPAIR];
    __shared__ int gbase[NPAIR];
    __shared__ float limp[16];
    int tid = threadIdx.x;
    if (tid < NPAIR) lcount[tid] = 0;
    if (tid < 16) limp[tid] = 0.f;

    int tokbase = blockIdx.x * 128;
    const float4* x4 = (const float4*)x;
    int rbase = tid >> 3, c4 = tid & 7;   // 32 row-groups x 8 float4 (32 dims/chunk)

    float4 pre[4];
#pragma unroll
    for (int i = 0; i < 4; ++i)
        pre[i] = x4[(size_t)(tokbase + i * 32 + rbase) * 64 + c4];

    int tk = tid >> 1;            // token within block
    int half = tid & 1;           // expert group: half*5 .. half*5+4
    float acc[5];
#pragma unroll
    for (int e = 0; e < 5; e++) acc[e] = 0.f;

    for (int cc = 0; cc < 8; ++cc) {
        float* buf = Xs[cc & 1];
#pragma unroll
        for (int i = 0; i < 4; ++i) {
            float* d = &buf[(i * 32 + rbase) * 33 + c4 * 4];
            d[0] = pre[i].x; d[1] = pre[i].y; d[2] = pre[i].z; d[3] = pre[i].w;
        }
        if (cc < 7) {
#pragma unroll
            for (int i = 0; i < 4; ++i)
                pre[i] = x4[(size_t)(tokbase + i * 32 + rbase) * 64 + (cc + 1) * 8 + c4];
        }
        __syncthreads();   // single barrier/chunk: double buffer protects reuse
        const float* wgc = wg + cc * 32 * NE + half * 5;
#pragma unroll
        for (int c = 0; c < 32; ++c) {
            float xv = buf[tk * 33 + c];
#pragma unroll
            for (int e = 0; e < 5; ++e)
                acc[e] = fmaf(xv, wgc[c * NE + e], acc[e]);
        }
    }

    // merge halves: adjacent lanes swap their 5 partial logits
    float oth[5];
#pragma unroll
    for (int e = 0; e < 5; ++e) oth[e] = __shfl_xor(acc[e], 1, 64);

    // divergent compute + LDS atomics (legal); NO barriers inside this branch
    int p = 0, lp = 0;
    float g0 = 0.f;
    if (half == 0) {
        float l[NE];
#pragma unroll
        for (int e = 0; e < 5; ++e) { l[e] = acc[e]; l[5 + e] = oth[e]; }
        // top-2 (first occurrence wins ties, matches lax.top_k)
        float l0 = -INFINITY, l1 = -INFINITY;
        int i0 = 0, i1 = 0;
#pragma unroll
        for (int e = 0; e < NE; e++) {
            float v = l[e];
            if (v > l0) { l1 = l0; i1 = i0; l0 = v; i0 = e; }
            else if (v > l1) { l1 = v; i1 = e; }
        }
        float ex = __expf(l1 - l0);
        g0 = 1.f / (1.f + ex);
        p = i0 * NE + i1;
        lp = atomicAdd(&lcount[p], 1);
        atomicAdd(&limp[i0], g0);
        atomicAdd(&limp[i1], 1.f - g0);
    }
    __syncthreads();                     // uniform
    if (tid < NPAIR) {
        int c = lcount[tid];
        gbase[tid] = c ? atomicAdd(&pcount[tid], c) : 0;
    }
    if (tid < NE) atomicAdd(&importance[tid], limp[tid]);
    __syncthreads();                     // uniform
    if (half == 0) {
        int pos = gbase[p] + lp;
        btok[p * T_TOKENS + pos] = tokbase + tk;
        bg0[p * T_TOKENS + pos] = g0;
    }
}

// ---------------- Kernel 2: build tile work-queue (parallel prefix scan) --------------------------
__global__ __launch_bounds__(128) void queue_kernel(
    const int* __restrict__ pcount,
    int* __restrict__ qp, int* __restrict__ qs, int* __restrict__ nq)
{
    __shared__ int nt[128];
    int tid = threadIdx.x;
    int c = (tid < NPAIR) ? pcount[tid] : 0;
    int t = (c + 63) >> 6;
    nt[tid] = t;
    __syncthreads();
    for (int o = 1; o < 128; o <<= 1) {           // Hillis-Steele inclusive scan
        int v = nt[tid];
        int add = (tid >= o) ? nt[tid - o] : 0;
        __syncthreads();
        nt[tid] = v + add;
        __syncthreads();
    }
    int startq = nt[tid] - t;
    for (int i = 0; i < t; i++) { qp[startq + i] = tid; qs[startq + i] = i * 64; }
    if (tid == 127) *nq = nt[127];
}

// ---------------- Kernel 3: fused pair-FFN; A-side bf16 (hi only), B-side split hi/lo ------------
__global__ __launch_bounds__(256, 4) void expert_kernel(
    const float* __restrict__ x,
    const unsigned short* __restrict__ w1ph, const unsigned short* __restrict__ w1pl,
    const unsigned short* __restrict__ w2ph, const unsigned short* __restrict__ w2pl,
    const float* __restrict__ b1, const float* __restrict__ b2,
    const int* __restrict__ pcount, const int* __restrict__ qp, const int* __restrict__ qs,
    const int* __restrict__ nq,
    const int* __restrict__ btok, const float* __restrict__ bg0,
    float* __restrict__ out, float* __restrict__ kdpart)
{
    int bid = blockIdx.x;
    if (bid >= *nq) return;
    int p = qp[bid], s = qs[bid];
    int e0 = p / NE, e1 = p - e0 * NE;
    int m = min(64, pcount[p] - s);

    __shared__ __align__(16) unsigned short Xh[64 * XROW];        // 9.2 KB
    __shared__ __align__(16) unsigned short H0h[4096], H1h[4096]; // 16 KB, A-frag order
    __shared__ int toks[64];
    __shared__ float gv0s[64], gv1s[64];
    __shared__ float kdw[4];
    // total ~26.4 KB -> 4 blocks/CU

    int tid = threadIdx.x;
    if (tid < 64) {
        int v = 0; float g = 0.f;
        if (tid < m) {
            v = btok[p * T_TOKENS + s + tid];
            g = bg0[p * T_TOKENS + s + tid];
        }
        toks[tid] = v;
        gv0s[tid] = g;
        gv1s[tid] = (tid < m) ? (1.f - g) : 0.f;
    }
    __syncthreads();

    int lane = tid & 63, wv = tid >> 6;
    int ln15 = lane & 15, quad = lane >> 4;
    int srow = tid >> 2, sc0 = (tid & 3) * 16;
    const float* xrow = x + (size_t)toks[srow] * EMBED;
    bool srow_ok = srow < m;

    f32x4 a10[4], a11[4];
#pragma unroll
    for (int rt = 0; rt < 4; ++rt) { a10[rt] = (f32x4){0,0,0,0}; a11[rt] = (f32x4){0,0,0,0}; }

    const unsigned short* w1h0 = w1ph + (((size_t)e0 * 4 + wv) * 8) * 512;
    const unsigned short* w1l0 = w1pl + (((size_t)e0 * 4 + wv) * 8) * 512;
    const unsigned short* w1h1 = w1ph + (((size_t)e1 * 4 + wv) * 8) * 512;
    const unsigned short* w1l1 = w1pl + (((size_t)e1 * 4 + wv) * 8) * 512;

    for (int cc = 0; cc < 4; ++cc) {                 // K chunks of 64
#pragma unroll
        for (int p4 = 0; p4 < 4; ++p4) {
            int col = sc0 + p4 * 4;
            float4 v = make_float4(0.f, 0.f, 0.f, 0.f);
            if (srow_ok) v = *(const float4*)(xrow + cc * 64 + col);
            const float* vs = (const float*)&v;
            ushort4 hv;
            unsigned short* hp = (unsigned short*)&hv;
#pragma unroll
            for (int i = 0; i < 4; ++i) hp[i] = f2bf(vs[i]);
            *(ushort4*)&Xh[srow * XROW + col] = hv;
        }
        __syncthreads();
#pragma unroll
        for (int kb = 0; kb < 2; ++kb) {
            int kbg = cc * 2 + kb;
            short8 bh0 = *(const short8*)(w1h0 + (size_t)kbg * 512 + lane * 8);
            short8 bl0 = *(const short8*)(w1l0 + (size_t)kbg * 512 + lane * 8);
            short8 bh1 = *(const short8*)(w1h1 + (size_t)kbg * 512 + lane * 8);
            short8 bl1 = *(const short8*)(w1l1 + (size_t)kbg * 512 + lane * 8);
            int aoff = kb * 32 + quad * 8;
#pragma unroll
            for (int rt = 0; rt < 4; ++rt) {
                short8 ah = *(const short8*)&Xh[(rt * 16 + ln15) * XROW + aoff];
                a10[rt] = __builtin_amdgcn_mfma_f32_16x16x32_bf16(ah, bh0, a10[rt], 0, 0, 0);
                a10[rt] = __builtin_amdgcn_mfma_f32_16x16x32_bf16(ah, bl0, a10[rt], 0, 0, 0);
                a11[rt] = __builtin_amdgcn_mfma_f32_16x16x32_bf16(ah, bh1, a11[rt], 0, 0, 0);
                a11[rt] = __builtin_amdgcn_mfma_f32_16x16x32_bf16(ah, bl1, a11[rt], 0, 0, 0);
            }
        }
        __syncthreads();
    }

    // H epilogue: bias+relu, pre-scale by gates, store hi-bf16 in A-frag order.
    // element (m,k) of tile (rt,kb): lane'=(k>>3)*16+m, j=k&7.
    {
        float b1v0 = b1[e0 * DOWN + wv * 16 + ln15];
        float b1v1 = b1[e1 * DOWN + wv * 16 + ln15];
        int kbH = wv >> 1;
        int laneH = (((wv & 1) * 2 + (ln15 >> 3)) * 16) + quad * 4;
        int jH = ln15 & 7;
#pragma unroll
        for (int rt = 0; rt < 4; ++rt) {
#pragma unroll
            for (int r = 0; r < 4; ++r) {
                int row = rt * 16 + quad * 4 + r;
                float h0 = fmaxf(a10[rt][r] + b1v0, 0.f) * gv0s[row];
                float h1 = fmaxf(a11[rt][r] + b1v1, 0.f) * gv1s[row];
                int idx = ((rt * 2 + kbH) * 64 + laneH + r) * 8 + jH;
                H0h[idx] = f2bf(h0);
                H1h[idx] = f2bf(h1);
            }
        }
    }
    __syncthreads();

    // GEMM2: y = (g0 h0) w2_e0 + (g1 h1) w2_e1 (+gated biases); KD + 0.5 scale in epilogue
    float b20[4], b21[4];
#pragma unroll
    for (int ci = 0; ci < 4; ++ci) {
        b20[ci] = b2[e0 * EMBED + (wv * 4 + ci) * 16 + ln15];
        b21[ci] = b2[e1 * EMBED + (wv * 4 + ci) * 16 + ln15];
    }
    float kdacc = 0.f;
#pragma unroll
    for (int rt = 0; rt < 4; ++rt) {
        short8 ah0[2], ah1[2];
#pragma unroll
        for (int kb = 0; kb < 2; ++kb) {
            int base = ((rt * 2 + kb) * 64 + lane) * 8;   // contiguous 16B/lane
            ah0[kb] = *(const short8*)&H0h[base];
            ah1[kb] = *(const short8*)&H1h[base];
        }
        int rowb = rt * 16 + quad * 4;
        float gr0[4], gr1[4];
#pragma unroll
        for (int r = 0; r < 4; ++r) { gr0[r] = gv0s[rowb + r]; gr1[r] = gv1s[rowb + r]; }
#pragma unroll
        for (int ci = 0; ci < 4; ++ci) {
            int ct = wv * 4 + ci;
            const unsigned short* p0h = w2ph + (((size_t)e0 * 16 + ct) * 2) * 512;
            const unsigned short* p0l = w2pl + (((size_t)e0 * 16 + ct) * 2) * 512;
            const unsigned short* p1h = w2ph + (((size_t)e1 * 16 + ct) * 2) * 512;
            const unsigned short* p1l = w2pl + (((size_t)e1 * 16 + ct) * 2) * 512;
            f32x4 acc = (f32x4){0, 0, 0, 0};
#pragma unroll
            for (int kb = 0; kb < 2; ++kb) {
                short8 bh = *(const short8*)(p0h + kb * 512 + lane * 8);
                short8 bl = *(const short8*)(p0l + kb * 512 + lane * 8);
                acc = __builtin_amdgcn_mfma_f32_16x16x32_bf16(ah0[kb], bh, acc, 0, 0, 0);
                acc = __builtin_amdgcn_mfma_f32_16x16x32_bf16(ah0[kb], bl, acc, 0, 0, 0);
                short8 ch = *(const short8*)(p1h + kb * 512 + lane * 8);
                short8 cl = *(const short8*)(p1l + kb * 512 + lane * 8);
                acc = __builtin_amdgcn_mfma_f32_16x16x32_bf16(ah1[kb], ch, acc, 0, 0, 0);
                acc = __builtin_amdgcn_mfma_f32_16x16x32_bf16(ah1[kb], cl, acc, 0, 0, 0);
            }
#pragma unroll
            for (int r = 0; r < 4; ++r) {
                int row = rowb + r;
                float val = acc[r] + gr0[r] * b20[ci] + gr1[r] * b21[ci];  // unscaled y
                if (row < m) {
                    kdacc += fabsf(val);
                    out[(size_t)toks[row] * EMBED + ct * 16 + ln15] = 0.5f * val;
                }
            }
        }
    }
    // KD block reduction
#pragma unroll
    for (int o = 32; o > 0; o >>= 1) kdacc += __shfl_down(kdacc, o, 64);
    if (lane == 0) kdw[wv] = kdacc;
    __syncthreads();
    if (tid == 0)
        atomicAdd(&kdpart[bid & 63], kdw[0] + kdw[1] + kdw[2] + kdw[3]);
}

// ---------------- Kernel 4: aux CV loss + kd loss (parallel loads) -------------------------------
__global__ __launch_bounds__(64) void loss_kernel(
    const int* __restrict__ pcount, const float* __restrict__ importance,
    const float* __restrict__ kdpart, float* __restrict__ loss_out)
{
    __shared__ float simp[16], sload[16];
    int tid = threadIdx.x;
    float kd = kdpart[tid];
#pragma unroll
    for (int o = 32; o > 0; o >>= 1) kd += __shfl_down(kd, o, 64);
    if (tid < NE) {
        float l = 0.f;
        for (int j = 0; j < NE; j++)
            l += (float)(pcount[tid * NE + j] + pcount[j * NE + tid]);
        sload[tid] = l;
        simp[tid] = importance[tid];
    }
    __syncthreads();
    if (tid == 0) {
        kd *= (1.f / (float)((size_t)T_TOKENS * EMBED));
        float mi = 0.f, ml = 0.f;
        for (int e = 0; e < NE; e++) { mi += simp[e]; ml += sload[e]; }
        mi *= (1.f / NE); ml *= (1.f / NE);
        float vi = 0.f, vl = 0.f;
        for (int e = 0; e < NE; e++) {
            float di = simp[e] - mi; vi += di * di;
            float dl = sload[e] - ml; vl += dl * dl;
        }
        vi *= (1.f / (NE - 1)); vl *= (1.f / (NE - 1));   // ddof=1
        float aux = vi / (mi * mi + 1e-10f) + vl / (ml * ml + 1e-10f);
        loss_out[0] = aux + kd;
    }
}

extern "C" void kernel_launch(void* const* d_in, const int* in_sizes, int n_in,
                              void* d_out, int out_size, void* d_ws, size_t ws_size,
                              hipStream_t stream)
{
    (void)in_sizes; (void)n_in; (void)out_size; (void)ws_size;
    const float* x  = (const float*)d_in[0];
    const float* wg = (const float*)d_in[1];
    const float* w1 = (const float*)d_in[2];
    const float* b1 = (const float*)d_in[3];
    const float* w2 = (const float*)d_in[4];
    const float* b2 = (const float*)d_in[5];
    float* out = (float*)d_out;

    char* ws = (char*)d_ws;
    int*   pcount     = (int*)ws;                  // 128 ints (100 used)
    float* importance = (float*)(ws + 512);        // 16 floats
    float* kdpart     = (float*)(ws + 576);        // 64 floats
    int*   nq         = (int*)(ws + 832);
    int*   qp         = (int*)(ws + 1024);         // MAXQ ints
    int*   qs         = (int*)(ws + 1024 + MAXQ * 4);
    size_t off = 16384;
    int*   btok = (int*)(ws + off);    off += (size_t)NPAIR * T_TOKENS * 4;   // 26.2 MB
    float* bg0  = (float*)(ws + off);  off += (size_t)NPAIR * T_TOKENS * 4;   // 26.2 MB
    unsigned short* w1ph = (unsigned short*)(ws + off); off += 327680;
    unsigned short* w1pl = (unsigned short*)(ws + off); off += 327680;
    unsigned short* w2ph = (unsigned short*)(ws + off); off += 327680;
    unsigned short* w2pl = (unsigned short*)(ws + off); off += 327680;

    hipMemsetAsync(ws, 0, 1024, stream);   // pcount + importance + kdpart + nq

    pack_kernel<<<160, 256, 0, stream>>>(w1, w2, w1ph, w1pl, w2ph, w2pl);
    gating_kernel<<<T_TOKENS / 128, 256, 0, stream>>>(x, wg, pcount, importance, btok, bg0);
    queue_kernel<<<1, 128, 0, stream>>>(pcount, qp, qs, nq);
    expert_kernel<<<1114, 256, 0, stream>>>(
        x, w1ph, w1pl, w2ph, w2pl, b1, b2, pcount, qp, qs, nq, btok, bg0, out, kdpart);
    loss_kernel<<<1, 64, 0, stream>>>(pcount, importance, kdpart, out + (size_t)T_TOKENS * EMBED);
}